// Round 3
// baseline (195.046 us; speedup 1.0000x reference)
//
#include <hip/hip_runtime.h>
#include <hip/hip_bf16.h>

#define STEP_F (1.0f/9.0f)

// ---------------- conv1: 3->8, 256x256 -> 127x127 (stored 127x128), stride 2, relu ----
// thread = (b, oh, ow-group-of-4); computes all 8 co. Weights fully-uniform -> s_load.
__global__ __launch_bounds__(256) void conv1_k(const float* __restrict__ x,
                                               const float* __restrict__ w,
                                               const float* __restrict__ bias,
                                               float* __restrict__ y)
{
    int idx = blockIdx.x * 256 + threadIdx.x;
    int owg = idx & 31;
    int t1  = idx >> 5;
    int oh  = t1 % 127;
    int b   = t1 / 127;
    int iw0 = owg * 8;
    int ih0 = oh * 2;
    const float* xb = x + (size_t)b * 3 * 65536;

    float acc[8][4];
    #pragma unroll
    for (int c = 0; c < 8; ++c)
        #pragma unroll
        for (int t = 0; t < 4; ++t) acc[c][t] = 0.0f;

    #pragma unroll
    for (int ci = 0; ci < 3; ++ci) {
        float r[3][10];
        #pragma unroll
        for (int kh = 0; kh < 3; ++kh) {
            const float* row = xb + ci * 65536 + (ih0 + kh) * 256;
            #pragma unroll
            for (int t = 0; t < 5; ++t) {
                int c = iw0 + 2 * t; if (c > 254) c = 254;   // only affects padded col 127
                float2 v = *(const float2*)(row + c);
                r[kh][2*t] = v.x; r[kh][2*t+1] = v.y;
            }
        }
        #pragma unroll
        for (int co = 0; co < 8; ++co) {
            float wr[9];
            #pragma unroll
            for (int k = 0; k < 9; ++k) wr[k] = w[(co * 3 + ci) * 9 + k];  // uniform -> s_load
            #pragma unroll
            for (int t = 0; t < 4; ++t) {
                float a = acc[co][t];
                #pragma unroll
                for (int kh = 0; kh < 3; ++kh)
                    a = fmaf(r[kh][2*t+0], wr[kh*3+0],
                        fmaf(r[kh][2*t+1], wr[kh*3+1],
                        fmaf(r[kh][2*t+2], wr[kh*3+2], a)));
                acc[co][t] = a;
            }
        }
    }
    int ow0 = owg * 4;
    #pragma unroll
    for (int co = 0; co < 8; ++co) {
        float bs = bias[co];
        float4 o;
        o.x = fmaxf(acc[co][0] + bs, 0.0f);
        o.y = fmaxf(acc[co][1] + bs, 0.0f);
        o.z = fmaxf(acc[co][2] + bs, 0.0f);
        o.w = fmaxf(acc[co][3] + bs, 0.0f);
        // row stride 128 -> 16B-aligned vector store; col 127 is pad (never read)
        *(float4*)(y + (((size_t)b * 8 + co) * 127 + oh) * 128 + ow0) = o;
    }
}

// ---------------- convs 2-5: LDS input tile + LDS-resident weights ----------------
// Block: (b, oh-tile, 16-co slice). 4 waves x 4 co each. Weights padded to 12 floats
// per (co,ci) -> 3x ds_read_b128 wave-uniform broadcast; zero VMEM in inner loop.
template<int CI, int CO, int IH, int IW, int XSTR, int OH, int OW, int OSTR, int RPT, int CICH>
__global__ __launch_bounds__(256) void convt2_k(
    const float* __restrict__ x, const float* __restrict__ w,
    const float* __restrict__ bias,
    const float* __restrict__ g, const float* __restrict__ be,
    const float* __restrict__ mn, const float* __restrict__ vr,
    float* __restrict__ y)
{
    constexpr int RS  = IW + 1;                 // pow2 LDS row stride
    constexpr int OWS = RS / 2;                 // lane slots per row
    constexpr int NR  = 64 / OWS;
    constexpr int OHT = NR * RPT;
    constexpr int TIH = (2*OHT+1) < IH ? (2*OHT+1) : IH;
    constexpr int STR = 256 / RS;
    constexpr int NCH = CI / CICH;              // ci chunks

    __shared__ float lw[16 * CI * 12];
    __shared__ float lin[CICH * TIH * RS + 2 * RS + 16];

    const int b       = blockIdx.x;
    const int oh_base = blockIdx.y * OHT;
    const int co_base = blockIdx.z * 16;

    {   // stage weights for this 16-co tile (contiguous in w), pad 9 -> 12
        const float* wp = w + (size_t)co_base * CI * 9;
        for (int i = threadIdx.x; i < 16 * CI * 9; i += 256)
            lw[(i / 9) * 12 + (i % 9)] = wp[i];
    }

    const int lane = threadIdx.x & 63;
    const int wv   = threadIdx.x >> 6;
    const int ow   = lane & (OWS - 1);
    const int r0   = lane / OWS;
    const int co0  = wv * 4;

    float acc[4][RPT];
    #pragma unroll
    for (int c = 0; c < 4; ++c)
        #pragma unroll
        for (int j = 0; j < RPT; ++j) acc[c][j] = 0.0f;

    const int ih0  = oh_base * 2;
    const int tihc = (TIH < IH - ih0) ? TIH : (IH - ih0);
    const int col  = threadIdx.x & (RS - 1);
    const int rp0  = threadIdx.x / RS;

    for (int cc = 0; cc < NCH; ++cc) {
        if (col < IW) {
            for (int ci = 0; ci < CICH; ++ci) {
                const float* gp = x + (((size_t)b * CI + cc * CICH + ci) * IH + ih0) * XSTR + col;
                float* lp = lin + (ci * TIH) * RS + col;
                for (int rr = rp0; rr < tihc; rr += STR)
                    lp[rr * RS] = gp[(size_t)rr * XSTR];
            }
        }
        __syncthreads();
        #pragma unroll 2
        for (int ci = 0; ci < CICH; ++ci) {
            float wr[4][12];
            #pragma unroll
            for (int c = 0; c < 4; ++c) {
                const float4* wl = (const float4*)(lw + (((size_t)(co0 + c)) * CI + cc * CICH + ci) * 12);
                float4 a0 = wl[0], a1 = wl[1], a2 = wl[2];
                wr[c][0]=a0.x; wr[c][1]=a0.y; wr[c][2]=a0.z; wr[c][3]=a0.w;
                wr[c][4]=a1.x; wr[c][5]=a1.y; wr[c][6]=a1.z; wr[c][7]=a1.w;
                wr[c][8]=a2.x;
            }
            const float* lci = lin + ci * TIH * RS;
            #pragma unroll
            for (int j = 0; j < RPT; ++j) {
                #pragma unroll
                for (int kh = 0; kh < 3; ++kh) {
                    const float* lr = lci + (2 * (r0 * RPT + j) + kh) * RS + 2 * ow;
                    float x0 = lr[0], x1 = lr[1], x2 = lr[2];
                    #pragma unroll
                    for (int c = 0; c < 4; ++c)
                        acc[c][j] = fmaf(x0, wr[c][kh*3+0],
                                    fmaf(x1, wr[c][kh*3+1],
                                    fmaf(x2, wr[c][kh*3+2], acc[c][j])));
                }
            }
        }
        __syncthreads();
    }

    #pragma unroll
    for (int c = 0; c < 4; ++c) {
        const int co = co_base + co0 + c;
        const float bs = bias[co];
        const float s  = g[co] / sqrtf(vr[co] + 1e-5f);
        const float sh = be[co] - mn[co] * s;
        if (ow < OW) {
            #pragma unroll
            for (int j = 0; j < RPT; ++j) {
                int oh = oh_base + r0 * RPT + j;
                if (oh < OH)
                    y[(((size_t)b * CO + co) * OH + oh) * OSTR + ow] =
                        fmaxf(acc[c][j] + bs, 0.0f) * s + sh;
            }
        }
    }
}

// ---------------- fused tail: mean + fc1 + fc2 + Thomas + splines LUT ----------------
// One block per batch image.
__global__ __launch_bounds__(256) void tail_k(
    const float* __restrict__ y5, const float* __restrict__ l1w,
    const float* __restrict__ l1b, const float* __restrict__ l2w,
    const float* __restrict__ l2b, float* __restrict__ coef,
    float* __restrict__ spl)
{
    __shared__ float feat[128];
    __shared__ float hh[128];
    __shared__ float ysv[64];
    __shared__ float cfl[216];
    const int b = blockIdx.x, t = threadIdx.x;

    if (t < 128) {                                  // mean over 7x7 (stride-8 rows)
        const float* p = y5 + ((size_t)b * 128 + t) * 56;
        float s = 0.0f;
        #pragma unroll
        for (int r = 0; r < 7; ++r)
            #pragma unroll
            for (int c = 0; c < 7; ++c) s += p[r * 8 + c];
        feat[t] = s * (1.0f / 49.0f);
    }
    __syncthreads();
    if (t < 128) {                                  // fc1 + relu
        const float4* wp = (const float4*)(l1w + (size_t)t * 128);
        float s = l1b[t];
        #pragma unroll 8
        for (int k = 0; k < 32; ++k) {
            float4 v = wp[k];
            s += v.x*feat[4*k] + v.y*feat[4*k+1] + v.z*feat[4*k+2] + v.w*feat[4*k+3];
        }
        hh[t] = fmaxf(s, 0.0f);
    }
    __syncthreads();
    if (t < 60) {                                   // fc2
        const float4* wp = (const float4*)(l2w + (size_t)t * 128);
        float s = l2b[t];
        #pragma unroll 8
        for (int k = 0; k < 32; ++k) {
            float4 v = wp[k];
            s += v.x*hh[4*k] + v.y*hh[4*k+1] + v.z*hh[4*k+2] + v.w*hh[4*k+3];
        }
        ysv[t] = s;
    }
    __syncthreads();
    if (t < 6) {                                    // natural cubic spline coeffs
        const float h = STEP_F;
        float yt[10];
        #pragma unroll
        for (int n = 0; n < 10; ++n) yt[n] = ysv[t * 10 + n] + (float)n * h;
        float r[8];
        const float k6h2 = 6.0f / (h * h);
        #pragma unroll
        for (int i = 0; i < 8; ++i) r[i] = k6h2 * (yt[i] - 2.0f * yt[i+1] + yt[i+2]);
        float cp[8], dp[8];
        cp[0] = 0.25f; dp[0] = r[0] * 0.25f;
        #pragma unroll
        for (int i = 1; i < 8; ++i) {
            float m = 4.0f - cp[i-1];
            cp[i] = 1.0f / m;
            dp[i] = (r[i] - dp[i-1]) / m;
        }
        float M[10];
        M[0] = 0.0f; M[9] = 0.0f; M[8] = dp[7];
        #pragma unroll
        for (int i = 6; i >= 0; --i) M[i+1] = dp[i] - cp[i] * M[i+2];
        float* cg = coef + ((size_t)b * 6 + t) * 36;
        #pragma unroll
        for (int i = 0; i < 9; ++i) {
            float ca = (M[i+1] - M[i]) / (6.0f * h);
            float cb = M[i] * 0.5f;
            float cc = (yt[i+1] - yt[i]) / h - (M[i+1] + 2.0f * M[i]) * (h / 6.0f);
            float cd = yt[i];
            cfl[t*36 + i]      = ca;  cg[i]      = ca;
            cfl[t*36 + 9 + i]  = cb;  cg[9 + i]  = cb;
            cfl[t*36 + 18 + i] = cc;  cg[18 + i] = cc;
            cfl[t*36 + 27 + i] = cd;  cg[27 + i] = cd;
        }
    }
    __syncthreads();
    for (int i = t; i < 1530; i += 256) {           // splines LUT (E,B,3,255)
        int v = i % 255, ec = i / 255;
        float val = (float)v * (1.0f / 255.0f);
        int vi = (int)floorf(val / STEP_F);
        vi = vi < 0 ? 0 : (vi > 8 ? 8 : vi);
        float vf = val - (float)vi * STEP_F;
        const float* c = cfl + ec * 36;
        int e = ec / 3, ch = ec % 3;
        spl[(((size_t)e * 64 + b) * 3 + ch) * 255 + v] =
            ((c[vi]*vf + c[9+vi])*vf + c[18+vi])*vf + c[27+vi];
    }
}

// ---------------- apply spline to batch pixels ----------------
__global__ __launch_bounds__(256) void apply_k(const float* __restrict__ batch,
                                               const float* __restrict__ coef,
                                               float* __restrict__ out)
{
    __shared__ float cf[72];
    int bc = blockIdx.y;
    int b = bc / 3, ch = bc % 3;
    if (threadIdx.x < 72) {
        int e = threadIdx.x / 36;
        int j = threadIdx.x % 36;
        cf[threadIdx.x] = coef[((size_t)(b * 6 + e * 3 + ch)) * 36 + j];
    }
    __syncthreads();

    const int P = 65536;
    size_t base = ((size_t)b * 3 + ch) * P;
    int p0 = (blockIdx.x * blockDim.x + threadIdx.x) * 4;

    float4 xv = *(const float4*)(batch + base + p0);
    float r0[4], r1[4];
    float xs[4] = {xv.x, xv.y, xv.z, xv.w};
    #pragma unroll
    for (int k = 0; k < 4; ++k) {
        float x = xs[k];
        int xi = (int)floorf(x / STEP_F);
        xi = xi < 0 ? 0 : (xi > 8 ? 8 : xi);
        float xf = x - (float)xi * STEP_F;
        {
            const float* c = cf;
            r0[k] = ((c[xi] * xf + c[9 + xi]) * xf + c[18 + xi]) * xf + c[27 + xi];
        }
        {
            const float* c = cf + 36;
            r1[k] = ((c[xi] * xf + c[9 + xi]) * xf + c[18 + xi]) * xf + c[27 + xi];
        }
    }
    float4 o0 = {r0[0], r0[1], r0[2], r0[3]};
    float4 o1 = {r1[0], r1[1], r1[2], r1[3]};
    size_t off0 = (((size_t)0 * 64 + b) * 3 + ch) * P + p0;
    size_t off1 = (((size_t)1 * 64 + b) * 3 + ch) * P + p0;
    *(float4*)(out + off0) = o0;
    *(float4*)(out + off1) = o1;
}

extern "C" void kernel_launch(void* const* d_in, const int* in_sizes, int n_in,
                              void* d_out, int out_size, void* d_ws, size_t ws_size,
                              hipStream_t stream) {
    const float* batch = (const float*)d_in[0];
    const float* w1 = (const float*)d_in[1];  const float* b1 = (const float*)d_in[2];
    const float* w2 = (const float*)d_in[3];  const float* b2 = (const float*)d_in[4];
    const float* w3 = (const float*)d_in[5];  const float* b3 = (const float*)d_in[6];
    const float* w4 = (const float*)d_in[7];  const float* b4 = (const float*)d_in[8];
    const float* w5 = (const float*)d_in[9];  const float* b5 = (const float*)d_in[10];
    const float* bn2g = (const float*)d_in[11]; const float* bn2b = (const float*)d_in[12];
    const float* bn2m = (const float*)d_in[13]; const float* bn2v = (const float*)d_in[14];
    const float* bn3g = (const float*)d_in[15]; const float* bn3b = (const float*)d_in[16];
    const float* bn3m = (const float*)d_in[17]; const float* bn3v = (const float*)d_in[18];
    const float* bn4g = (const float*)d_in[19]; const float* bn4b = (const float*)d_in[20];
    const float* bn4m = (const float*)d_in[21]; const float* bn4v = (const float*)d_in[22];
    const float* bn5g = (const float*)d_in[23]; const float* bn5b = (const float*)d_in[24];
    const float* bn5m = (const float*)d_in[25]; const float* bn5v = (const float*)d_in[26];
    const float* l1w = (const float*)d_in[27]; const float* l1b = (const float*)d_in[28];
    const float* l2w = (const float*)d_in[29]; const float* l2b = (const float*)d_in[30];

    float* outp = (float*)d_out;
    // Padded intermediates in the (later overwritten) out region:
    float* y1 = outp;                 // 64*8*127*128  = 8,323,072
    float* y2 = y1 + 8323072;         // 64*16*63*64   = 4,128,768
    float* y3 = y2 + 4128768;         // 64*32*31*32   = 2,031,616
    float* y4 = y3 + 2031616;         // 64*64*15*16   =   983,040
    float* y5 = y4 + 983040;          // 64*128*7*8    =   458,752
    // end = 15,925,248 < 25,165,824 -> safe.

    float* coef = (float*)d_ws;       // 64*6*36 = 13,824 floats

    const int TPB = 256;
    conv1_k<<<1016, TPB, 0, stream>>>(batch, w1, b1, y1);
    // conv2: 8->16, 127->63
    convt2_k<8, 16, 127, 127, 128, 63, 63, 64, 4, 8>
        <<<dim3(64, 16, 1), TPB, 0, stream>>>(y1, w2, b2, bn2g, bn2b, bn2m, bn2v, y2);
    // conv3: 16->32, 63->31
    convt2_k<16, 32, 63, 63, 64, 31, 31, 32, 2, 16>
        <<<dim3(64, 8, 2), TPB, 0, stream>>>(y2, w3, b3, bn3g, bn3b, bn3m, bn3v, y3);
    // conv4: 32->64, 31->15
    convt2_k<32, 64, 31, 31, 32, 15, 15, 16, 1, 32>
        <<<dim3(64, 4, 4), TPB, 0, stream>>>(y3, w4, b4, bn4g, bn4b, bn4m, bn4v, y4);
    // conv5: 64->128, 15->7 (4 ci-chunks of 16)
    convt2_k<64, 128, 15, 15, 16, 7, 7, 8, 1, 16>
        <<<dim3(64, 1, 8), TPB, 0, stream>>>(y4, w5, b5, bn5g, bn5b, bn5m, bn5v, y5);
    // fused tail
    tail_k<<<64, TPB, 0, stream>>>(y5, l1w, l1b, l2w, l2b, coef, outp + 25165824);
    // apply
    {
        dim3 grid(64, 192);
        apply_k<<<grid, TPB, 0, stream>>>(batch, coef, outp);
    }
}